// Round 21
// baseline (6432.767 us; speedup 1.0000x reference)
//
#include <hip/hip_runtime.h>

#define TT 1500
#define BB 96
#define VV 128
#define LGT 256
#define LCAP 512
#define NEGF (-1.0e30f)
#define L2E 1.4426950408889634f
#define LN2F 0.6931471805599453f
#define NW 11  // waves per CTC block (704 threads)
#define GH 34  // ghost states: 2*HREF=32 < 34; oS(<=94)+34 <= 128
#define HREF 16

// ---------------------------------------------------------------------------
// Kernel 1: greedy decode (unchanged).
// ---------------------------------------------------------------------------
__global__ __launch_bounds__(256) void decode_kernel(
    const float* __restrict__ acts, const int* __restrict__ act_lens,
    int* __restrict__ dec, int* __restrict__ dec_lens) {
  __shared__ int preds[TT];
  __shared__ int sc[256];
  const int b = blockIdx.x;
  const int tid = threadIdx.x;
  const int Tl = act_lens[b];
  for (int t = tid; t < Tl; t += 256) {
    const float4* r4 = (const float4*)(acts + ((size_t)t * BB + b) * VV);
    float best = -3.4e38f;
    int bi = 0;
#pragma unroll
    for (int i = 0; i < VV / 4; i++) {
      float4 v = r4[i];
      if (v.x > best) { best = v.x; bi = 4 * i; }
      if (v.y > best) { best = v.y; bi = 4 * i + 1; }
      if (v.z > best) { best = v.z; bi = 4 * i + 2; }
      if (v.w > best) { best = v.w; bi = 4 * i + 3; }
    }
    preds[t] = bi;
  }
  __syncthreads();

  int pv[6];
  bool fl[6];
  int cnt = 0;
#pragma unroll
  for (int j = 0; j < 6; j++) {
    int t = tid * 6 + j;
    bool valid = t < Tl;
    int p = valid ? preds[t] : 0;
    int pr = (t == 0) ? -1 : (valid ? preds[t - 1] : -1);
    bool f = valid && (p != 0) && (p != pr);
    pv[j] = p;
    fl[j] = f;
    cnt += f;
  }
  sc[tid] = cnt;
  __syncthreads();
  for (int off = 1; off < 256; off <<= 1) {
    int v = sc[tid];
    if (tid >= off) v += sc[tid - off];
    __syncthreads();
    sc[tid] = v;
    __syncthreads();
  }
  int pos = sc[tid] - cnt;  // exclusive prefix
  int total = sc[255];
  int* db = dec + (size_t)b * LCAP;
#pragma unroll
  for (int j = 0; j < 6; j++) {
    if (fl[j]) {
      if (pos < LCAP) db[pos] = pv[j];
      pos++;
    }
  }
  if (tid == 0) {
    if (total == 0) db[0] = 0;
    dec_lens[b] = max(1, min(total, LCAP));
  }
}

// ---------------------------------------------------------------------------
// Kernel 2: CTC, r20 structure (334us, absmax 0.0). SINGLE TWEAK: Estrin-form
// log1p poly (same coefficients; dependency depth ~24cy -> ~14cy) with the
// final p*w*L2E fold. Everything else byte-identical.
// ---------------------------------------------------------------------------
__device__ __forceinline__ float shr1_negf(float x) {
  // lane i <- lane i-1's x; lane 0 <- NEGF.  DPP ctrl 0x138 = wave_shr:1.
  int r = __builtin_amdgcn_update_dpp(__float_as_int(NEGF), __float_as_int(x),
                                      0x138, 0xf, 0xf, false);
  return __int_as_float(r);
}

// log2(1+x) for x in [0,1]; poly only (no trans), Estrin form. err < 1e-4.
__device__ __forceinline__ float log1p2f(float x) {
  float w = __builtin_fmaf(x, 0.6666666666666666f, -0.3333333333333333f);
  float w2 = w * w;
  float wl = w * L2E;
  float P01 = __builtin_fmaf(w, -0.5f, 1.0f);
  float P23 = __builtin_fmaf(w, -0.25f, 0.3333333333333333f);
  float P45 = __builtin_fmaf(w, -0.16666666666666666f, 0.2f);
  float w4 = w2 * w2;
  float p = __builtin_fmaf(w2, P23, P01);
  p = __builtin_fmaf(w4, P45, p);
  // log2(1+x) = p*w*L2E + (log2(3) - 1)
  return __builtin_fmaf(p, wl, 0.5849625007211562f);
}

__global__ __launch_bounds__(64 * NW, 1) void ctc_kernel(
    const float* __restrict__ acts, const int* __restrict__ labels_gt,
    const int* __restrict__ act_lens, const int* __restrict__ label_lens,
    const int* __restrict__ dec, const int* __restrict__ dec_lens,
    float* __restrict__ ends) {
  __shared__ float xall[2][2 * LCAP + 2];  // parity double buffer
  __shared__ float fin[2];
  const int b = blockIdx.x >> 1;
  const int hyp = blockIdx.x & 1;
  const int Tl = act_lens[b];
  const int len = hyp ? dec_lens[b] : label_lens[b];
  const int* lab = hyp ? (dec + (size_t)b * LCAP) : (labels_gt + (size_t)b * LGT);
  const int S = 2 * len + 1;
  const float* act_b = acts + (size_t)b * VV;  // acts[(t*BB + b)*VV + v]
  const int Tlm1 = Tl - 1;

  const int tid = threadIdx.x;
  const int lane = tid & 63, wv = tid >> 6;
  const int oS = 2 * ((S + 2 * NW - 1) / (2 * NW));  // even owned span (<=94)
  const int Se = (S + 1) & ~1;
  const int o0 = min(wv * oS, Se);  // even
  const int o1 = min(o0 + oS, S);
  const int p0 = max(0, o0 - GH);   // even ghost bottom
  const int s0 = p0 + 2 * lane;     // blank state (even)
  const int s1 = s0 + 1;            // label state (odd)

  int e1 = 0;
  bool skip = false;
  if (s1 < S) {
    int li = s1 >> 1;
    e1 = lab[li];
    if (s1 >= 3) skip = (e1 != 0) && (e1 != lab[li - 1]);
  }

  float a0 = NEGF, a1 = NEGF;
  if (wv == 0 && lane == 0) {
    a0 = act_b[0] * L2E;
    a1 = act_b[e1] * L2E;  // S >= 3 always (len >= 1)
  }

  float gL0, gL1, gL2, gL3, gL4, gL5, gL6, gL7;  // label logits (gather)
  float gB0, gB1, gB2, gB3, gB4, gB5, gB6, gB7;  // blank logits (uniform)

#define PREF(GL, GB, ROW)                                  \
  {                                                        \
    const float* rp_ = act_b + (size_t)(ROW) * (BB * VV);  \
    GB = rp_[0];                                           \
    GL = rp_[e1];                                          \
  }

#define STEPK(GL, GB)                                                     \
  {                                                                       \
    float pe = shr1_negf(a1);                                             \
    /* u = lse2(a0, pe) via exp2 + poly log1p */                          \
    float m0 = fmaxf(a0, pe);                                             \
    float d0 = fminf(a0, pe) - m0;                                        \
    float u = m0 + log1p2f(__builtin_exp2f(d0));                          \
    /* v = lse2(a1, w), w = skip ? u : a0 */                              \
    float w = skip ? u : a0;                                              \
    float m1 = fmaxf(a1, w);                                              \
    float d1 = fminf(a1, w) - m1;                                         \
    float v = m1 + log1p2f(__builtin_exp2f(d1));                          \
    a0 = __builtin_fmaf(GB, L2E, u);                                      \
    a1 = __builtin_fmaf(GL, L2E, v);                                      \
  }

  // ONE-barrier refresh with parity buffer (vmcnt prefetch stays in flight)
#define REFRESH(K)                                       \
  {                                                      \
    float* xs = xall[(K)&1];                             \
    if (s0 >= o0 && s0 < o1) xs[s0] = a0;                \
    if (s1 >= o0 && s1 < o1) xs[s1] = a1;                \
    asm volatile("s_waitcnt lgkmcnt(0)" ::: "memory");   \
    __builtin_amdgcn_s_barrier();                        \
    if (s0 < o0) {                                       \
      a0 = xs[s0];                                       \
      a1 = (s1 < S) ? xs[s1] : NEGF;                     \
    }                                                    \
  }

  // window step: consume slot, refill same slot with row t+OFF+8
#define W1(OFF, GL, GB)                    \
  STEPK(GL, GB);                           \
  PREF(GL, GB, min(t + (OFF) + 8, Tlm1));

  // tail step: same rotation, with exit checks
#define T1(GL, GB)                         \
  STEPK(GL, GB);                           \
  PREF(GL, GB, min(t + 8, Tlm1));          \
  ++t;                                     \
  if (t >= Tl) break;

  // prologue: slots 0..7 = rows 1..8 (clamped)
  PREF(gL0, gB0, min(1, Tlm1));
  PREF(gL1, gB1, min(2, Tlm1));
  PREF(gL2, gB2, min(3, Tlm1));
  PREF(gL3, gB3, min(4, Tlm1));
  PREF(gL4, gB4, min(5, Tlm1));
  PREF(gL5, gB5, min(6, Tlm1));
  PREF(gL6, gB6, min(7, Tlm1));
  PREF(gL7, gB7, min(8, Tlm1));

  int t = 1, k = 0;
  // main: branch-free 16-step windows; one-barrier refresh per window
  while (t + HREF <= Tl) {
    W1(0, gL0, gB0)
    W1(1, gL1, gB1)
    W1(2, gL2, gB2)
    W1(3, gL3, gB3)
    W1(4, gL4, gB4)
    W1(5, gL5, gB5)
    W1(6, gL6, gB6)
    W1(7, gL7, gB7)
    W1(8, gL0, gB0)
    W1(9, gL1, gB1)
    W1(10, gL2, gB2)
    W1(11, gL3, gB3)
    W1(12, gL4, gB4)
    W1(13, gL5, gB5)
    W1(14, gL6, gB6)
    W1(15, gL7, gB7)
    t += HREF;
    ++k;
    REFRESH(k);
  }
  // tail: <= 15 steps (ghost covers 2*15=30 < 34), slots aligned (16%8==0)
  while (t < Tl) {
    T1(gL0, gB0)
    T1(gL1, gB1)
    T1(gL2, gB2)
    T1(gL3, gB3)
    T1(gL4, gB4)
    T1(gL5, gB5)
    T1(gL6, gB6)
    T1(gL7, gB7)
  }
#undef T1
#undef W1
#undef REFRESH
#undef STEPK
#undef PREF

  // end = logaddexp(al[2*len], al[2*len-1]) from owned states
  __syncthreads();
  if (s0 >= o0 && s0 < o1 && s0 == 2 * len) fin[0] = a0;
  if (s1 >= o0 && s1 < o1 && s1 == 2 * len - 1) fin[1] = a1;
  __syncthreads();
  if (tid == 0) {
    float a = fin[0], c = fin[1];
    float m = fmaxf(a, c);
    float e = m + __builtin_log2f(__builtin_exp2f(a - m) + __builtin_exp2f(c - m));
    ends[hyp * BB + b] = e;
  }
}

// ---------------------------------------------------------------------------
// Clock probes: 1,048,576-deep DEPENDENT fma chain (~4 cy/FMA dep latency,
// learn_hip m07). P1: 64 thr/block (1 wave/CU) -> pure chain.
//   f_GHz ~= 4194 / dur_us  (1667us @2.4GHz, 2857us @1.4GHz)
// P2: same chain at the real kernel's config (704 thr + 80KB LDS) -> in-situ.
// ---------------------------------------------------------------------------
__global__ __launch_bounds__(64) void clock_probe1(float* __restrict__ sink) {
  float a = (float)(threadIdx.x + blockIdx.x * 64) * 1e-7f + 1.0f;
  for (int i = 0; i < 16384; ++i) {
#pragma unroll
    for (int j = 0; j < 64; ++j) a = __builtin_fmaf(a, 1.0000001f, 1e-9f);
  }
  if (threadIdx.x == 0) sink[blockIdx.x] = a;
}

__global__ __launch_bounds__(64 * NW, 1) void clock_probe2(
    float* __restrict__ sink) {
  __shared__ float dummy[64];
  float a = (float)(threadIdx.x + blockIdx.x) * 1e-7f + 1.0f;
  for (int i = 0; i < 16384; ++i) {
#pragma unroll
    for (int j = 0; j < 64; ++j) a = __builtin_fmaf(a, 1.0000001f, 1e-9f);
  }
  dummy[threadIdx.x & 63] = a;
  __syncthreads();
  if (threadIdx.x == 0) sink[blockIdx.x] = dummy[0];
}

// ---------------------------------------------------------------------------
// Kernel 3: out[b] = (end_hyp' - end_gt') * ln2 + 1.0  (log2-domain ends)
// ---------------------------------------------------------------------------
__global__ void final_kernel(const float* __restrict__ ends,
                             float* __restrict__ out) {
  int b = threadIdx.x;
  if (b < BB) out[b] = (ends[BB + b] - ends[b]) * LN2F + 1.0f;
}

extern "C" void kernel_launch(void* const* d_in, const int* in_sizes, int n_in,
                              void* d_out, int out_size, void* d_ws,
                              size_t ws_size, hipStream_t stream) {
  const float* acts = (const float*)d_in[0];
  const int* labels = (const int*)d_in[1];
  const int* act_lens = (const int*)d_in[2];
  const int* label_lens = (const int*)d_in[3];
  float* out = (float*)d_out;

  char* ws = (char*)d_ws;
  int* dec = (int*)ws;                                 // B*LCAP ints
  size_t off = (size_t)BB * LCAP * 4;
  int* dec_lens = (int*)(ws + off);                    // B ints
  off += BB * 4;
  float* ends = (float*)(ws + off);                    // 2*B floats
  off += 2 * BB * 4;
  float* sinkA = (float*)(ws + off);                   // 2*B floats (probes)
  off += 2 * BB * 4;
  float* sinkB = (float*)(ws + off);                   // 2*B floats

  decode_kernel<<<dim3(BB), dim3(256), 0, stream>>>(acts, act_lens, dec, dec_lens);
  // 80KB dynamic LDS (+8.2KB static): 1 block/CU -> 2.75 waves/SIMD.
  ctc_kernel<<<dim3(2 * BB), dim3(64 * NW), 80 * 1024, stream>>>(
      acts, labels, act_lens, label_lens, dec, dec_lens, ends);
  final_kernel<<<dim3(1), dim3(128), 0, stream>>>(ends, out);
  // --- clock probes (sacrificial timing this round) ---
  clock_probe1<<<dim3(2 * BB), dim3(64), 0, stream>>>(sinkA);
  clock_probe2<<<dim3(2 * BB), dim3(64 * NW), 80 * 1024, stream>>>(sinkB);
}

// Round 22
// 439.677 us; speedup vs baseline: 14.6307x; 14.6307x over previous
//
#include <hip/hip_runtime.h>

#define TT 1500
#define BB 96
#define VV 128
#define LGT 256
#define LCAP 512
#define NEGF (-1.0e30f)
#define L2E 1.4426950408889634f
#define LN2F 0.6931471805599453f
#define NW 16   // waves per CTC block (1024 threads) -> 4 waves/SIMD
#define GH 34   // ghost states: 2*HREF=32 < 34; oS(<=66)+34 <= 128
#define HREF 16

// ---------------------------------------------------------------------------
// Kernel 1: greedy decode (unchanged).
// ---------------------------------------------------------------------------
__global__ __launch_bounds__(256) void decode_kernel(
    const float* __restrict__ acts, const int* __restrict__ act_lens,
    int* __restrict__ dec, int* __restrict__ dec_lens) {
  __shared__ int preds[TT];
  __shared__ int sc[256];
  const int b = blockIdx.x;
  const int tid = threadIdx.x;
  const int Tl = act_lens[b];
  for (int t = tid; t < Tl; t += 256) {
    const float4* r4 = (const float4*)(acts + ((size_t)t * BB + b) * VV);
    float best = -3.4e38f;
    int bi = 0;
#pragma unroll
    for (int i = 0; i < VV / 4; i++) {
      float4 v = r4[i];
      if (v.x > best) { best = v.x; bi = 4 * i; }
      if (v.y > best) { best = v.y; bi = 4 * i + 1; }
      if (v.z > best) { best = v.z; bi = 4 * i + 2; }
      if (v.w > best) { best = v.w; bi = 4 * i + 3; }
    }
    preds[t] = bi;
  }
  __syncthreads();

  int pv[6];
  bool fl[6];
  int cnt = 0;
#pragma unroll
  for (int j = 0; j < 6; j++) {
    int t = tid * 6 + j;
    bool valid = t < Tl;
    int p = valid ? preds[t] : 0;
    int pr = (t == 0) ? -1 : (valid ? preds[t - 1] : -1);
    bool f = valid && (p != 0) && (p != pr);
    pv[j] = p;
    fl[j] = f;
    cnt += f;
  }
  sc[tid] = cnt;
  __syncthreads();
  for (int off = 1; off < 256; off <<= 1) {
    int v = sc[tid];
    if (tid >= off) v += sc[tid - off];
    __syncthreads();
    sc[tid] = v;
    __syncthreads();
  }
  int pos = sc[tid] - cnt;  // exclusive prefix
  int total = sc[255];
  int* db = dec + (size_t)b * LCAP;
#pragma unroll
  for (int j = 0; j < 6; j++) {
    if (fl[j]) {
      if (pos < LCAP) db[pos] = pv[j];
      pos++;
    }
  }
  if (tid == 0) {
    if (total == 0) db[0] = 0;
    dec_lens[b] = max(1, min(total, LCAP));
  }
}

// ---------------------------------------------------------------------------
// Kernel 2: CTC, r20/r21 structure. CHANGES: (1) NW 11->16 (4 waves/SIMD,
// fills the measured ~45% issue-idle; still 1 block/CU via 76KB dyn LDS);
// (2) leaner lse2: exp2(-|a-b|) via free neg-abs modifiers (fmin deleted)
// and L2E-prescaled log1p coefficients (Estrin, 9 ops; separate w*L2E mul
// deleted). Step ~= 28 VALU + 2 trans (was ~34 + 2).
// ---------------------------------------------------------------------------
__device__ __forceinline__ float shr1_negf(float x) {
  // lane i <- lane i-1's x; lane 0 <- NEGF.  DPP ctrl 0x138 = wave_shr:1.
  int r = __builtin_amdgcn_update_dpp(__float_as_int(NEGF), __float_as_int(x),
                                      0x138, 0xf, 0xf, false);
  return __int_as_float(r);
}

// log2(1+x) for x in [0,1]: Estrin on L2E*ln(1+w), w=(2x-1)/3. err < 1e-4.
__device__ __forceinline__ float log1p2f(float x) {
  float w = __builtin_fmaf(x, 0.6666666666666666f, -0.3333333333333333f);
  float Q01 = __builtin_fmaf(w, -0.7213475204444817f, 1.4426950408889634f);
  float Q23 = __builtin_fmaf(w, -0.36067376022224085f, 0.4808983469629878f);
  float Q45 = __builtin_fmaf(w, -0.24044917348149392f, 0.2885390081777927f);
  float w2 = w * w;
  float w4 = w2 * w2;
  float r = __builtin_fmaf(w2, Q23, Q01);
  r = __builtin_fmaf(w4, Q45, r);
  // log2(1+x) = r*w + (log2(3) - 1)
  return __builtin_fmaf(r, w, 0.5849625007211562f);
}

// lse2 in log2 domain: max(a,b) + log2(1 + 2^(-|a-b|)). No fmin (abs mod).
__device__ __forceinline__ float lse2f(float a, float b) {
  float m = fmaxf(a, b);
  float x = __builtin_exp2f(-__builtin_fabsf(a - b));  // src mods: free
  return m + log1p2f(x);
}

__global__ __launch_bounds__(64 * NW, 1) void ctc_kernel(
    const float* __restrict__ acts, const int* __restrict__ labels_gt,
    const int* __restrict__ act_lens, const int* __restrict__ label_lens,
    const int* __restrict__ dec, const int* __restrict__ dec_lens,
    float* __restrict__ ends) {
  __shared__ float xall[2][2 * LCAP + 2];  // parity double buffer
  __shared__ float fin[2];
  const int b = blockIdx.x >> 1;
  const int hyp = blockIdx.x & 1;
  const int Tl = act_lens[b];
  const int len = hyp ? dec_lens[b] : label_lens[b];
  const int* lab = hyp ? (dec + (size_t)b * LCAP) : (labels_gt + (size_t)b * LGT);
  const int S = 2 * len + 1;
  const float* act_b = acts + (size_t)b * VV;  // acts[(t*BB + b)*VV + v]
  const int Tlm1 = Tl - 1;

  const int tid = threadIdx.x;
  const int lane = tid & 63, wv = tid >> 6;
  const int oS = 2 * ((S + 2 * NW - 1) / (2 * NW));  // even owned span (<=66)
  const int Se = (S + 1) & ~1;
  const int o0 = min(wv * oS, Se);  // even
  const int o1 = min(o0 + oS, S);
  const int p0 = max(0, o0 - GH);   // even ghost bottom
  const int s0 = p0 + 2 * lane;     // blank state (even)
  const int s1 = s0 + 1;            // label state (odd)

  int e1 = 0;
  bool skip = false;
  if (s1 < S) {
    int li = s1 >> 1;
    e1 = lab[li];
    if (s1 >= 3) skip = (e1 != 0) && (e1 != lab[li - 1]);
  }

  float a0 = NEGF, a1 = NEGF;
  if (wv == 0 && lane == 0) {
    a0 = act_b[0] * L2E;
    a1 = act_b[e1] * L2E;  // S >= 3 always (len >= 1)
  }

  float gL0, gL1, gL2, gL3, gL4, gL5, gL6, gL7;  // label logits (gather)
  float gB0, gB1, gB2, gB3, gB4, gB5, gB6, gB7;  // blank logits (uniform)

#define PREF(GL, GB, ROW)                                  \
  {                                                        \
    const float* rp_ = act_b + (size_t)(ROW) * (BB * VV);  \
    GB = rp_[0];                                           \
    GL = rp_[e1];                                          \
  }

#define STEPK(GL, GB)                                                     \
  {                                                                       \
    float pe = shr1_negf(a1);                                             \
    float u = lse2f(a0, pe);                                              \
    float w = skip ? u : a0;                                              \
    float v = lse2f(a1, w);                                               \
    a0 = __builtin_fmaf(GB, L2E, u);                                      \
    a1 = __builtin_fmaf(GL, L2E, v);                                      \
  }

  // ONE-barrier refresh with parity buffer (vmcnt prefetch stays in flight)
#define REFRESH(K)                                       \
  {                                                      \
    float* xs = xall[(K)&1];                             \
    if (s0 >= o0 && s0 < o1) xs[s0] = a0;                \
    if (s1 >= o0 && s1 < o1) xs[s1] = a1;                \
    asm volatile("s_waitcnt lgkmcnt(0)" ::: "memory");   \
    __builtin_amdgcn_s_barrier();                        \
    if (s0 < o0) {                                       \
      a0 = xs[s0];                                       \
      a1 = (s1 < S) ? xs[s1] : NEGF;                     \
    }                                                    \
  }

  // window step: consume slot, refill same slot with row t+OFF+8
#define W1(OFF, GL, GB)                    \
  STEPK(GL, GB);                           \
  PREF(GL, GB, min(t + (OFF) + 8, Tlm1));

  // tail step: same rotation, with exit checks
#define T1(GL, GB)                         \
  STEPK(GL, GB);                           \
  PREF(GL, GB, min(t + 8, Tlm1));          \
  ++t;                                     \
  if (t >= Tl) break;

  // prologue: slots 0..7 = rows 1..8 (clamped)
  PREF(gL0, gB0, min(1, Tlm1));
  PREF(gL1, gB1, min(2, Tlm1));
  PREF(gL2, gB2, min(3, Tlm1));
  PREF(gL3, gB3, min(4, Tlm1));
  PREF(gL4, gB4, min(5, Tlm1));
  PREF(gL5, gB5, min(6, Tlm1));
  PREF(gL6, gB6, min(7, Tlm1));
  PREF(gL7, gB7, min(8, Tlm1));

  int t = 1, k = 0;
  // main: branch-free 16-step windows; one-barrier refresh per window
  while (t + HREF <= Tl) {
    W1(0, gL0, gB0)
    W1(1, gL1, gB1)
    W1(2, gL2, gB2)
    W1(3, gL3, gB3)
    W1(4, gL4, gB4)
    W1(5, gL5, gB5)
    W1(6, gL6, gB6)
    W1(7, gL7, gB7)
    W1(8, gL0, gB0)
    W1(9, gL1, gB1)
    W1(10, gL2, gB2)
    W1(11, gL3, gB3)
    W1(12, gL4, gB4)
    W1(13, gL5, gB5)
    W1(14, gL6, gB6)
    W1(15, gL7, gB7)
    t += HREF;
    ++k;
    REFRESH(k);
  }
  // tail: <= 15 steps (ghost covers 2*15=30 < 34), slots aligned (16%8==0)
  while (t < Tl) {
    T1(gL0, gB0)
    T1(gL1, gB1)
    T1(gL2, gB2)
    T1(gL3, gB3)
    T1(gL4, gB4)
    T1(gL5, gB5)
    T1(gL6, gB6)
    T1(gL7, gB7)
  }
#undef T1
#undef W1
#undef REFRESH
#undef STEPK
#undef PREF

  // end = logaddexp(al[2*len], al[2*len-1]) from owned states
  __syncthreads();
  if (s0 >= o0 && s0 < o1 && s0 == 2 * len) fin[0] = a0;
  if (s1 >= o0 && s1 < o1 && s1 == 2 * len - 1) fin[1] = a1;
  __syncthreads();
  if (tid == 0) {
    float a = fin[0], c = fin[1];
    float m = fmaxf(a, c);
    float e = m + __builtin_log2f(__builtin_exp2f(a - m) + __builtin_exp2f(c - m));
    ends[hyp * BB + b] = e;
  }
}

// ---------------------------------------------------------------------------
// Kernel 3: out[b] = (end_hyp' - end_gt') * ln2 + 1.0  (log2-domain ends)
// ---------------------------------------------------------------------------
__global__ void final_kernel(const float* __restrict__ ends,
                             float* __restrict__ out) {
  int b = threadIdx.x;
  if (b < BB) out[b] = (ends[BB + b] - ends[b]) * LN2F + 1.0f;
}

extern "C" void kernel_launch(void* const* d_in, const int* in_sizes, int n_in,
                              void* d_out, int out_size, void* d_ws,
                              size_t ws_size, hipStream_t stream) {
  const float* acts = (const float*)d_in[0];
  const int* labels = (const int*)d_in[1];
  const int* act_lens = (const int*)d_in[2];
  const int* label_lens = (const int*)d_in[3];
  float* out = (float*)d_out;

  char* ws = (char*)d_ws;
  int* dec = (int*)ws;                                          // B*LCAP ints
  int* dec_lens = (int*)(ws + (size_t)BB * LCAP * 4);           // B ints
  float* ends = (float*)(ws + (size_t)BB * LCAP * 4 + BB * 4);  // 2*B floats

  decode_kernel<<<dim3(BB), dim3(256), 0, stream>>>(acts, act_lens, dec, dec_lens);
  // 76KB dynamic LDS (+8.2KB static = 84.2KB): 1 block/CU -> 4 waves/SIMD.
  ctc_kernel<<<dim3(2 * BB), dim3(64 * NW), 76 * 1024, stream>>>(
      acts, labels, act_lens, label_lens, dec, dec_lens, ends);
  final_kernel<<<dim3(1), dim3(128), 0, stream>>>(ends, out);
}

// Round 23
// 363.040 us; speedup vs baseline: 17.7192x; 1.2111x over previous
//
#include <hip/hip_runtime.h>

#define TT 1500
#define BB 96
#define VV 128
#define LGT 256
#define LCAP 512
#define NEGF (-1.0e30f)
#define L2E 1.4426950408889634f
#define LN2F 0.6931471805599453f
#define NW 11   // waves per CTC block (704 threads) — min for R=2: oS+GH<=128
#define GH 34   // ghost states: 2*HREF=32 < 34; oS(<=94)+34 <= 128
#define HREF 16

// ---------------------------------------------------------------------------
// Kernel 1: greedy decode (unchanged).
// ---------------------------------------------------------------------------
__global__ __launch_bounds__(256) void decode_kernel(
    const float* __restrict__ acts, const int* __restrict__ act_lens,
    int* __restrict__ dec, int* __restrict__ dec_lens) {
  __shared__ int preds[TT];
  __shared__ int sc[256];
  const int b = blockIdx.x;
  const int tid = threadIdx.x;
  const int Tl = act_lens[b];
  for (int t = tid; t < Tl; t += 256) {
    const float4* r4 = (const float4*)(acts + ((size_t)t * BB + b) * VV);
    float best = -3.4e38f;
    int bi = 0;
#pragma unroll
    for (int i = 0; i < VV / 4; i++) {
      float4 v = r4[i];
      if (v.x > best) { best = v.x; bi = 4 * i; }
      if (v.y > best) { best = v.y; bi = 4 * i + 1; }
      if (v.z > best) { best = v.z; bi = 4 * i + 2; }
      if (v.w > best) { best = v.w; bi = 4 * i + 3; }
    }
    preds[t] = bi;
  }
  __syncthreads();

  int pv[6];
  bool fl[6];
  int cnt = 0;
#pragma unroll
  for (int j = 0; j < 6; j++) {
    int t = tid * 6 + j;
    bool valid = t < Tl;
    int p = valid ? preds[t] : 0;
    int pr = (t == 0) ? -1 : (valid ? preds[t - 1] : -1);
    bool f = valid && (p != 0) && (p != pr);
    pv[j] = p;
    fl[j] = f;
    cnt += f;
  }
  sc[tid] = cnt;
  __syncthreads();
  for (int off = 1; off < 256; off <<= 1) {
    int v = sc[tid];
    if (tid >= off) v += sc[tid - off];
    __syncthreads();
    sc[tid] = v;
    __syncthreads();
  }
  int pos = sc[tid] - cnt;  // exclusive prefix
  int total = sc[255];
  int* db = dec + (size_t)b * LCAP;
#pragma unroll
  for (int j = 0; j < 6; j++) {
    if (fl[j]) {
      if (pos < LCAP) db[pos] = pv[j];
      pos++;
    }
  }
  if (tid == 0) {
    if (total == 0) db[0] = 0;
    dec_lens[b] = max(1, min(total, LCAP));
  }
}

// ---------------------------------------------------------------------------
// Kernel 2: CTC. Config = r20's proven best (NW=11, 2.75 waves/SIMD, 1
// block/CU, HREF=16 one-barrier refresh); math = r22's lean lse2
// (fmin-free exp2(-|a-b|) via src modifiers + L2E-prescaled Estrin log1p).
// Completes the {math} x {NW} 2x2: r20=old/11 (334us), r22=lean/16 (437us).
// ---------------------------------------------------------------------------
__device__ __forceinline__ float shr1_negf(float x) {
  // lane i <- lane i-1's x; lane 0 <- NEGF.  DPP ctrl 0x138 = wave_shr:1.
  int r = __builtin_amdgcn_update_dpp(__float_as_int(NEGF), __float_as_int(x),
                                      0x138, 0xf, 0xf, false);
  return __int_as_float(r);
}

// log2(1+x) for x in [0,1]: Estrin on L2E*ln(1+w), w=(2x-1)/3. err < 1e-4.
__device__ __forceinline__ float log1p2f(float x) {
  float w = __builtin_fmaf(x, 0.6666666666666666f, -0.3333333333333333f);
  float Q01 = __builtin_fmaf(w, -0.7213475204444817f, 1.4426950408889634f);
  float Q23 = __builtin_fmaf(w, -0.36067376022224085f, 0.4808983469629878f);
  float Q45 = __builtin_fmaf(w, -0.24044917348149392f, 0.2885390081777927f);
  float w2 = w * w;
  float w4 = w2 * w2;
  float r = __builtin_fmaf(w2, Q23, Q01);
  r = __builtin_fmaf(w4, Q45, r);
  // log2(1+x) = r*w + (log2(3) - 1)
  return __builtin_fmaf(r, w, 0.5849625007211562f);
}

// lse2 in log2 domain: max(a,b) + log2(1 + 2^(-|a-b|)). No fmin (abs mod).
__device__ __forceinline__ float lse2f(float a, float b) {
  float m = fmaxf(a, b);
  float x = __builtin_exp2f(-__builtin_fabsf(a - b));  // src mods: free
  return m + log1p2f(x);
}

__global__ __launch_bounds__(64 * NW, 1) void ctc_kernel(
    const float* __restrict__ acts, const int* __restrict__ labels_gt,
    const int* __restrict__ act_lens, const int* __restrict__ label_lens,
    const int* __restrict__ dec, const int* __restrict__ dec_lens,
    float* __restrict__ ends) {
  __shared__ float xall[2][2 * LCAP + 2];  // parity double buffer
  __shared__ float fin[2];
  const int b = blockIdx.x >> 1;
  const int hyp = blockIdx.x & 1;
  const int Tl = act_lens[b];
  const int len = hyp ? dec_lens[b] : label_lens[b];
  const int* lab = hyp ? (dec + (size_t)b * LCAP) : (labels_gt + (size_t)b * LGT);
  const int S = 2 * len + 1;
  const float* act_b = acts + (size_t)b * VV;  // acts[(t*BB + b)*VV + v]
  const int Tlm1 = Tl - 1;

  const int tid = threadIdx.x;
  const int lane = tid & 63, wv = tid >> 6;
  const int oS = 2 * ((S + 2 * NW - 1) / (2 * NW));  // even owned span (<=94)
  const int Se = (S + 1) & ~1;
  const int o0 = min(wv * oS, Se);  // even
  const int o1 = min(o0 + oS, S);
  const int p0 = max(0, o0 - GH);   // even ghost bottom
  const int s0 = p0 + 2 * lane;     // blank state (even)
  const int s1 = s0 + 1;            // label state (odd)

  int e1 = 0;
  bool skip = false;
  if (s1 < S) {
    int li = s1 >> 1;
    e1 = lab[li];
    if (s1 >= 3) skip = (e1 != 0) && (e1 != lab[li - 1]);
  }

  float a0 = NEGF, a1 = NEGF;
  if (wv == 0 && lane == 0) {
    a0 = act_b[0] * L2E;
    a1 = act_b[e1] * L2E;  // S >= 3 always (len >= 1)
  }

  float gL0, gL1, gL2, gL3, gL4, gL5, gL6, gL7;  // label logits (gather)
  float gB0, gB1, gB2, gB3, gB4, gB5, gB6, gB7;  // blank logits (uniform)

#define PREF(GL, GB, ROW)                                  \
  {                                                        \
    const float* rp_ = act_b + (size_t)(ROW) * (BB * VV);  \
    GB = rp_[0];                                           \
    GL = rp_[e1];                                          \
  }

#define STEPK(GL, GB)                                                     \
  {                                                                       \
    float pe = shr1_negf(a1);                                             \
    float u = lse2f(a0, pe);                                              \
    float w = skip ? u : a0;                                              \
    float v = lse2f(a1, w);                                               \
    a0 = __builtin_fmaf(GB, L2E, u);                                      \
    a1 = __builtin_fmaf(GL, L2E, v);                                      \
  }

  // ONE-barrier refresh with parity buffer (vmcnt prefetch stays in flight)
#define REFRESH(K)                                       \
  {                                                      \
    float* xs = xall[(K)&1];                             \
    if (s0 >= o0 && s0 < o1) xs[s0] = a0;                \
    if (s1 >= o0 && s1 < o1) xs[s1] = a1;                \
    asm volatile("s_waitcnt lgkmcnt(0)" ::: "memory");   \
    __builtin_amdgcn_s_barrier();                        \
    if (s0 < o0) {                                       \
      a0 = xs[s0];                                       \
      a1 = (s1 < S) ? xs[s1] : NEGF;                     \
    }                                                    \
  }

  // window step: consume slot, refill same slot with row t+OFF+8
#define W1(OFF, GL, GB)                    \
  STEPK(GL, GB);                           \
  PREF(GL, GB, min(t + (OFF) + 8, Tlm1));

  // tail step: same rotation, with exit checks
#define T1(GL, GB)                         \
  STEPK(GL, GB);                           \
  PREF(GL, GB, min(t + 8, Tlm1));          \
  ++t;                                     \
  if (t >= Tl) break;

  // prologue: slots 0..7 = rows 1..8 (clamped)
  PREF(gL0, gB0, min(1, Tlm1));
  PREF(gL1, gB1, min(2, Tlm1));
  PREF(gL2, gB2, min(3, Tlm1));
  PREF(gL3, gB3, min(4, Tlm1));
  PREF(gL4, gB4, min(5, Tlm1));
  PREF(gL5, gB5, min(6, Tlm1));
  PREF(gL6, gB6, min(7, Tlm1));
  PREF(gL7, gB7, min(8, Tlm1));

  int t = 1, k = 0;
  // main: branch-free 16-step windows; one-barrier refresh per window
  while (t + HREF <= Tl) {
    W1(0, gL0, gB0)
    W1(1, gL1, gB1)
    W1(2, gL2, gB2)
    W1(3, gL3, gB3)
    W1(4, gL4, gB4)
    W1(5, gL5, gB5)
    W1(6, gL6, gB6)
    W1(7, gL7, gB7)
    W1(8, gL0, gB0)
    W1(9, gL1, gB1)
    W1(10, gL2, gB2)
    W1(11, gL3, gB3)
    W1(12, gL4, gB4)
    W1(13, gL5, gB5)
    W1(14, gL6, gB6)
    W1(15, gL7, gB7)
    t += HREF;
    ++k;
    REFRESH(k);
  }
  // tail: <= 15 steps (ghost covers 2*15=30 < 34), slots aligned (16%8==0)
  while (t < Tl) {
    T1(gL0, gB0)
    T1(gL1, gB1)
    T1(gL2, gB2)
    T1(gL3, gB3)
    T1(gL4, gB4)
    T1(gL5, gB5)
    T1(gL6, gB6)
    T1(gL7, gB7)
  }
#undef T1
#undef W1
#undef REFRESH
#undef STEPK
#undef PREF

  // end = logaddexp(al[2*len], al[2*len-1]) from owned states
  __syncthreads();
  if (s0 >= o0 && s0 < o1 && s0 == 2 * len) fin[0] = a0;
  if (s1 >= o0 && s1 < o1 && s1 == 2 * len - 1) fin[1] = a1;
  __syncthreads();
  if (tid == 0) {
    float a = fin[0], c = fin[1];
    float m = fmaxf(a, c);
    float e = m + __builtin_log2f(__builtin_exp2f(a - m) + __builtin_exp2f(c - m));
    ends[hyp * BB + b] = e;
  }
}

// ---------------------------------------------------------------------------
// Kernel 3: out[b] = (end_hyp' - end_gt') * ln2 + 1.0  (log2-domain ends)
// ---------------------------------------------------------------------------
__global__ void final_kernel(const float* __restrict__ ends,
                             float* __restrict__ out) {
  int b = threadIdx.x;
  if (b < BB) out[b] = (ends[BB + b] - ends[b]) * LN2F + 1.0f;
}

extern "C" void kernel_launch(void* const* d_in, const int* in_sizes, int n_in,
                              void* d_out, int out_size, void* d_ws,
                              size_t ws_size, hipStream_t stream) {
  const float* acts = (const float*)d_in[0];
  const int* labels = (const int*)d_in[1];
  const int* act_lens = (const int*)d_in[2];
  const int* label_lens = (const int*)d_in[3];
  float* out = (float*)d_out;

  char* ws = (char*)d_ws;
  int* dec = (int*)ws;                                          // B*LCAP ints
  int* dec_lens = (int*)(ws + (size_t)BB * LCAP * 4);           // B ints
  float* ends = (float*)(ws + (size_t)BB * LCAP * 4 + BB * 4);  // 2*B floats

  decode_kernel<<<dim3(BB), dim3(256), 0, stream>>>(acts, act_lens, dec, dec_lens);
  // 80KB dynamic LDS (+8.2KB static): 1 block/CU -> 2.75 waves/SIMD.
  ctc_kernel<<<dim3(2 * BB), dim3(64 * NW), 80 * 1024, stream>>>(
      acts, labels, act_lens, label_lens, dec, dec_lens, ends);
  final_kernel<<<dim3(1), dim3(128), 0, stream>>>(ends, out);
}